// Round 1
// baseline (315.247 us; speedup 1.0000x reference)
//
#include <hip/hip_runtime.h>

#define B_ 8
#define C_ 512
#define N_ 2304
#define CQ 64

typedef float f32x4 __attribute__((ext_vector_type(4)));
typedef short bf16x8 __attribute__((ext_vector_type(8)));
typedef unsigned short u16x8 __attribute__((ext_vector_type(8)));

__device__ __forceinline__ unsigned short f2bf(float f){
  union { float f; unsigned int u; } v; v.f = f;
  unsigned int r = (v.u + 0x7fffu + ((v.u >> 16) & 1u)) >> 16;
  return (unsigned short)r;
}

__device__ __forceinline__ void gload_lds16(const void* g, void* l){
  __builtin_amdgcn_global_load_lds(
      (const __attribute__((address_space(1))) unsigned int*)g,
      (__attribute__((address_space(3))) unsigned int*)l, 16, 0, 0);
}

// ---------------- transpose: x [B][C][N] f32 -> xt [B][N][C] bf16 ----------------
__global__ __launch_bounds__(256) void k_transpose(const float* __restrict__ x,
                                                   unsigned short* __restrict__ xt){
  __shared__ float T[64*68];
  int i = blockIdx.x;
  int b = i & 7; int r = i >> 3;          // r in [0, 288)
  int ct = r & 7, nt = r >> 3;            // 8 c-tiles, 36 n-tiles
  int c0 = ct << 6, n0 = nt << 6;
  int t = threadIdx.x;
  {
    int c = t >> 2, nn = (t & 3) << 4;
    const float* src = x + ((size_t)b*C_ + c0 + c)*N_ + n0 + nn;
    #pragma unroll
    for (int q = 0; q < 4; q++){
      f32x4 v = *(const f32x4*)(src + q*4);
      *(f32x4*)&T[c*68 + nn + q*4] = v;
    }
  }
  __syncthreads();
  {
    int n = t >> 2, cs = (t & 3) << 4;
    u16x8 h0, h1;
    #pragma unroll
    for (int ii = 0; ii < 8; ii++) h0[ii] = f2bf(T[(cs+ii)*68 + n]);
    #pragma unroll
    for (int ii = 0; ii < 8; ii++) h1[ii] = f2bf(T[(cs+8+ii)*68 + n]);
    unsigned short* d = xt + ((size_t)b*N_ + n0 + n)*C_ + c0 + cs;
    *(u16x8*)d = h0;
    *(u16x8*)(d + 8) = h1;
  }
}

// ---------------- projection GEMM: D_t[n,o] = sum_c xt[n,c] W[o,c] + b[o] ----------------
// MODE 0: Q -> center over o, scale 1/512, store [B][N][64] bf16
// MODE 1: K -> store [B][N][64] bf16
// MODE 2: V -> store [B][C][N] bf16
template<int MODE>
__global__ __launch_bounds__(256) void k_proj(const unsigned short* __restrict__ xt,
                                              const float* __restrict__ Wm,
                                              const float* __restrict__ bias,
                                              unsigned short* __restrict__ outw){
  __shared__ short Al[64*40];   // xt tile [64 n][32+8 c]
  __shared__ short Bl[64*40];   // W  tile [64 o][32+8 c]
  __shared__ float T[64*68];    // epilogue tile [n][o]
  int i = blockIdx.x;
  int b = i & 7; int r = i >> 3;
  int nt, o0;
  if (MODE == 2){ nt = r >> 3; o0 = (r & 7) << 6; } else { nt = r; o0 = 0; }
  int n0 = nt << 6;
  int t = threadIdx.x; int w = t >> 6; int l = t & 63;
  int cl = l & 15, g = l >> 4;
  int col = (w << 4) + cl;     // o within tile for this wave

  f32x4 acc[4];
  #pragma unroll
  for (int nf = 0; nf < 4; nf++) acc[nf] = (f32x4){0.f,0.f,0.f,0.f};

  for (int kk = 0; kk < 16; kk++){
    int c0k = kk << 5;
    { // stage A (xt, already bf16)
      int n = t >> 2, cs8 = (t & 3) << 3;
      u16x8 v = *(const u16x8*)(xt + ((size_t)b*N_ + n0 + n)*C_ + c0k + cs8);
      *(u16x8*)&Al[n*40 + cs8] = v;
    }
    { // stage B (W fp32 -> bf16)
      int o = t >> 2, cs8 = (t & 3) << 3;
      const float* s = Wm + (size_t)(o0 + o)*C_ + c0k + cs8;
      f32x4 v0 = *(const f32x4*)s;
      f32x4 v1 = *(const f32x4*)(s + 4);
      u16x8 h;
      #pragma unroll
      for (int j = 0; j < 4; j++) h[j] = f2bf(v0[j]);
      #pragma unroll
      for (int j = 0; j < 4; j++) h[4+j] = f2bf(v1[j]);
      *(u16x8*)&Bl[o*40 + cs8] = h;
    }
    __syncthreads();
    bf16x8 bfr = *(const bf16x8*)&Bl[col*40 + (g << 3)];
    #pragma unroll
    for (int nf = 0; nf < 4; nf++){
      bf16x8 afr = *(const bf16x8*)&Al[((nf << 4) + cl)*40 + (g << 3)];
      acc[nf] = __builtin_amdgcn_mfma_f32_16x16x32_bf16(afr, bfr, acc[nf], 0, 0, 0);
    }
    __syncthreads();
  }

  // frags (+bias) -> T[n][o]
  float bvv = bias[o0 + col];
  #pragma unroll
  for (int nf = 0; nf < 4; nf++)
    #pragma unroll
    for (int rr = 0; rr < 4; rr++)
      T[((nf << 4) + (g << 2) + rr)*68 + col] = acc[nf][rr] + bvv;
  __syncthreads();

  if (MODE == 2){
    int o = t >> 2, j = t & 3;
    u16x8 h0, h1;
    #pragma unroll
    for (int ii = 0; ii < 8; ii++) h0[ii] = f2bf(T[(j*16+ii)*68 + o]);
    #pragma unroll
    for (int ii = 0; ii < 8; ii++) h1[ii] = f2bf(T[(j*16+8+ii)*68 + o]);
    unsigned short* d = outw + ((size_t)b*C_ + o0 + o)*N_ + n0 + (j << 4);
    *(u16x8*)d = h0;
    *(u16x8*)(d + 8) = h1;
  } else {
    int n = t >> 2, j = t & 3;
    float vals[16]; float s = 0.f;
    #pragma unroll
    for (int ii = 0; ii < 16; ii++){ vals[ii] = T[n*68 + (j << 4) + ii]; s += vals[ii]; }
    s += __shfl_xor(s, 1); s += __shfl_xor(s, 2);
    float mean = (MODE == 0) ? s * (1.f/64.f) : 0.f;
    float scl  = (MODE == 0) ? (1.f/512.f)    : 1.f;
    u16x8 h0, h1;
    #pragma unroll
    for (int ii = 0; ii < 8; ii++) h0[ii] = f2bf((vals[ii]   - mean) * scl);
    #pragma unroll
    for (int ii = 0; ii < 8; ii++) h1[ii] = f2bf((vals[8+ii] - mean) * scl);
    unsigned short* d = outw + ((size_t)b*N_ + n0 + n)*CQ + (j << 4);
    *(u16x8*)d = h0;
    *(u16x8*)(d + 8) = h1;
  }
}

// ---------------- flash attention + residual ----------------
// Q tile 32 rows per block, 8 waves, KB=32. qw/kw: [B][N][64] bf16, vw: [B][C][N] bf16.
__global__ __launch_bounds__(512) void k_attn(const unsigned short* __restrict__ qw,
                                              const unsigned short* __restrict__ kw,
                                              const unsigned short* __restrict__ vw,
                                              const float* __restrict__ x,
                                              const float* __restrict__ gamma_p,
                                              float* __restrict__ out){
  __shared__ __align__(16) short Qs[32*64];    // [n][64c] rows 128B, chunk-rotated
  __shared__ __align__(16) short Ks[32*64];    // [m][64c]
  __shared__ __align__(16) short Vs[512*32];   // [c][32m] rows 64B, chunk-rotated
  __shared__ __align__(16) float Ss[32*33];    // raw scores
  __shared__ __align__(16) short Ps[32*32];    // P bf16, chunk-rotated
  __shared__ __align__(16) float scale_l[32];
  __shared__ __align__(16) float linv_l[32];

  int i = blockIdx.x; int b = i & 7; int qt = i >> 3;
  int n0 = qt << 5;
  int t = threadIdx.x; int w = t >> 6; int l = t & 63;
  int cl = l & 15, g = l >> 4;
  int sn = t >> 4, sj = t & 15;    // softmax row / lane-in-row

  // stage Q once (waves 0-3, 8 rows of 128B each)
  if (w < 4){
    int row = (w << 3) + (l >> 3);
    int sl = l & 7;
    int gc = (sl - (row & 7)) & 7;
    gload_lds16(qw + ((size_t)b*N_ + n0 + row)*CQ + (gc << 3), &Qs[(w << 3)*64]);
  }

  float m_run = -INFINITY, l_run = 0.f;
  f32x4 acc[2][4];
  #pragma unroll
  for (int nf = 0; nf < 2; nf++)
    #pragma unroll
    for (int cf = 0; cf < 4; cf++) acc[nf][cf] = (f32x4){0.f,0.f,0.f,0.f};

  for (int mt = 0; mt < N_/32; mt++){
    int m0 = mt << 5;
    // ---- stage K (waves 0-3) and V (all waves) ----
    if (w < 4){
      int row = (w << 3) + (l >> 3);
      int sl = l & 7;
      int gc = (sl - (row & 7)) & 7;
      gload_lds16(kw + ((size_t)b*N_ + m0 + row)*CQ + (gc << 3), &Ks[(w << 3)*64]);
    }
    #pragma unroll
    for (int qq = 0; qq < 4; qq++){
      int crow = (w << 6) + (qq << 4) + (l >> 2);
      int sl = l & 3;
      int gc = (sl - ((crow >> 1) & 3)) & 3;
      gload_lds16(vw + ((size_t)b*C_ + crow)*N_ + m0 + (gc << 3),
                  &Vs[((w << 6) + (qq << 4))*32]);
    }
    __syncthreads();

    // ---- S = Qc @ K^T (waves 0-3, one 16x16 frag each, K=64) ----
    if (w < 4){
      int nf = w >> 1, mf = w & 1;
      int arow = (nf << 4) + cl;
      int brow = (mf << 4) + cl;
      f32x4 sa = (f32x4){0.f,0.f,0.f,0.f};
      #pragma unroll
      for (int ks = 0; ks < 2; ks++){
        int gc = (ks << 2) + g;
        bf16x8 af = *(const bf16x8*)&Qs[arow*64 + (((gc + (arow & 7)) & 7) << 3)];
        bf16x8 bf = *(const bf16x8*)&Ks[brow*64 + (((gc + (brow & 7)) & 7) << 3)];
        sa = __builtin_amdgcn_mfma_f32_16x16x32_bf16(af, bf, sa, 0, 0, 0);
      }
      #pragma unroll
      for (int rr = 0; rr < 4; rr++)
        Ss[((nf << 4) + (g << 2) + rr)*33 + (mf << 4) + cl] = sa[rr];
    }
    __syncthreads();

    // ---- online softmax (all 512 threads; 16 lanes per row) ----
    {
      float s0 = Ss[sn*33 + 2*sj];
      float s1 = Ss[sn*33 + 2*sj + 1];
      float tm = fmaxf(s0, s1);
      tm = fmaxf(tm, __shfl_xor(tm, 1));
      tm = fmaxf(tm, __shfl_xor(tm, 2));
      tm = fmaxf(tm, __shfl_xor(tm, 4));
      tm = fmaxf(tm, __shfl_xor(tm, 8));
      float m_new = fmaxf(m_run, tm);
      float sc = __expf(m_run - m_new);
      float p0 = __expf(s0 - m_new);
      float p1 = __expf(s1 - m_new);
      float rs = p0 + p1;
      rs += __shfl_xor(rs, 1); rs += __shfl_xor(rs, 2);
      rs += __shfl_xor(rs, 4); rs += __shfl_xor(rs, 8);
      l_run = l_run * sc + rs;
      m_run = m_new;
      if (sj == 0) scale_l[sn] = sc;
      unsigned int pp = (unsigned int)f2bf(p0) | ((unsigned int)f2bf(p1) << 16);
      int slotp = ((sj >> 2) + ((sn >> 1) & 3)) & 3;
      *(unsigned int*)&Ps[sn*32 + (slotp << 3) + ((2*sj) & 7)] = pp;
    }
    __syncthreads();

    // ---- O = O*scale + P @ V  (each wave: c-slice w*64..w*64+63) ----
    {
      f32x4 sc0 = *(const f32x4*)&scale_l[g << 2];
      f32x4 sc1 = *(const f32x4*)&scale_l[16 + (g << 2)];
      #pragma unroll
      for (int cf = 0; cf < 4; cf++){ acc[0][cf] *= sc0; acc[1][cf] *= sc1; }
      int r0 = cl;      int sl0 = (g + ((r0 >> 1) & 3)) & 3;
      int r1 = 16 + cl; int sl1 = (g + ((r1 >> 1) & 3)) & 3;
      bf16x8 pa0 = *(const bf16x8*)&Ps[r0*32 + (sl0 << 3)];
      bf16x8 pa1 = *(const bf16x8*)&Ps[r1*32 + (sl1 << 3)];
      #pragma unroll
      for (int cf = 0; cf < 4; cf++){
        int crow = (w << 6) + (cf << 4) + cl;
        int slv = (g + ((crow >> 1) & 3)) & 3;
        bf16x8 vb = *(const bf16x8*)&Vs[crow*32 + (slv << 3)];
        acc[0][cf] = __builtin_amdgcn_mfma_f32_16x16x32_bf16(pa0, vb, acc[0][cf], 0, 0, 0);
        acc[1][cf] = __builtin_amdgcn_mfma_f32_16x16x32_bf16(pa1, vb, acc[1][cf], 0, 0, 0);
      }
    }
    __syncthreads();
  }

  if (sj == 0) linv_l[sn] = 1.f / l_run;
  __syncthreads();

  float gm = gamma_p[0];
  #pragma unroll
  for (int nf = 0; nf < 2; nf++){
    f32x4 li = *(const f32x4*)&linv_l[(nf << 4) + (g << 2)];
    #pragma unroll
    for (int cf = 0; cf < 4; cf++){
      int c = (w << 6) + (cf << 4) + cl;
      size_t base = ((size_t)b*C_ + c)*N_ + n0 + (nf << 4) + (g << 2);
      f32x4 xv = *(const f32x4*)&x[base];
      f32x4 o4;
      #pragma unroll
      for (int rr = 0; rr < 4; rr++) o4[rr] = acc[nf][cf][rr] * li[rr] * gm + xv[rr];
      *(f32x4*)&out[base] = o4;
    }
  }
}

extern "C" void kernel_launch(void* const* d_in, const int* in_sizes, int n_in,
                              void* d_out, int out_size, void* d_ws, size_t ws_size,
                              hipStream_t stream) {
  (void)in_sizes; (void)n_in; (void)out_size; (void)ws_size;
  const float* x  = (const float*)d_in[0];
  const float* Wq = (const float*)d_in[1];
  const float* bq = (const float*)d_in[2];
  const float* Wk = (const float*)d_in[3];
  const float* bk = (const float*)d_in[4];
  const float* Wv = (const float*)d_in[5];
  const float* bv = (const float*)d_in[6];
  const float* gm = (const float*)d_in[7];
  float* out = (float*)d_out;

  unsigned short* xt = (unsigned short*)d_ws;                 // [B][N][C] bf16
  unsigned short* qw = xt + (size_t)B_*N_*C_;                 // [B][N][64] bf16
  unsigned short* kw = qw + (size_t)B_*N_*CQ;                 // [B][N][64] bf16
  unsigned short* vw = kw + (size_t)B_*N_*CQ;                 // [B][C][N] bf16

  k_transpose<<<2304, 256, 0, stream>>>(x, xt);
  k_proj<0><<<288, 256, 0, stream>>>(xt, Wq, bq, qw);
  k_proj<1><<<288, 256, 0, stream>>>(xt, Wk, bk, kw);
  k_proj<2><<<2304, 256, 0, stream>>>(xt, Wv, bv, vw);
  k_attn<<<576, 512, 0, stream>>>(qw, kw, vw, x, gm, out);
}

// Round 2
// 196.733 us; speedup vs baseline: 1.6024x; 1.6024x over previous
//
#include <hip/hip_runtime.h>

#define B_ 8
#define C_ 512
#define N_ 2304
#define CQ 64

typedef float f32x4 __attribute__((ext_vector_type(4)));
typedef short bf16x8 __attribute__((ext_vector_type(8)));
typedef unsigned short u16x8 __attribute__((ext_vector_type(8)));

__device__ __forceinline__ unsigned short f2bf(float f){
  union { float f; unsigned int u; } v; v.f = f;
  unsigned int r = (v.u + 0x7fffu + ((v.u >> 16) & 1u)) >> 16;
  return (unsigned short)r;
}

__device__ __forceinline__ void gload_lds16(const void* g, void* l){
  __builtin_amdgcn_global_load_lds(
      (const __attribute__((address_space(1))) unsigned int*)g,
      (__attribute__((address_space(3))) unsigned int*)l, 16, 0, 0);
}

// ---------------- transpose: x [B][C][N] f32 -> xt [B][N][C] bf16 ----------------
__global__ __launch_bounds__(256) void k_transpose(const float* __restrict__ x,
                                                   unsigned short* __restrict__ xt){
  __shared__ float T[64*68];
  int i = blockIdx.x;
  int b = i & 7; int r = i >> 3;          // r in [0, 288)
  int ct = r & 7, nt = r >> 3;            // 8 c-tiles, 36 n-tiles
  int c0 = ct << 6, n0 = nt << 6;
  int t = threadIdx.x;
  {
    int c = t >> 2, nn = (t & 3) << 4;
    const float* src = x + ((size_t)b*C_ + c0 + c)*N_ + n0 + nn;
    #pragma unroll
    for (int q = 0; q < 4; q++){
      f32x4 v = *(const f32x4*)(src + q*4);
      *(f32x4*)&T[c*68 + nn + q*4] = v;
    }
  }
  __syncthreads();
  {
    int n = t >> 2, cs = (t & 3) << 4;
    u16x8 h0, h1;
    #pragma unroll
    for (int ii = 0; ii < 8; ii++) h0[ii] = f2bf(T[(cs+ii)*68 + n]);
    #pragma unroll
    for (int ii = 0; ii < 8; ii++) h1[ii] = f2bf(T[(cs+8+ii)*68 + n]);
    unsigned short* d = xt + ((size_t)b*N_ + n0 + n)*C_ + c0 + cs;
    *(u16x8*)d = h0;
    *(u16x8*)(d + 8) = h1;
  }
}

// ---------------- projection GEMM: D_t[n,o] = sum_c xt[n,c] W[o,c] + b[o] ----------------
template<int MODE>
__global__ __launch_bounds__(256) void k_proj(const unsigned short* __restrict__ xt,
                                              const float* __restrict__ Wm,
                                              const float* __restrict__ bias,
                                              unsigned short* __restrict__ outw){
  __shared__ short Al[64*40];
  __shared__ short Bl[64*40];
  __shared__ float T[64*68];
  int i = blockIdx.x;
  int b = i & 7; int r = i >> 3;
  int nt, o0;
  if (MODE == 2){ nt = r >> 3; o0 = (r & 7) << 6; } else { nt = r; o0 = 0; }
  int n0 = nt << 6;
  int t = threadIdx.x; int w = t >> 6; int l = t & 63;
  int cl = l & 15, g = l >> 4;
  int col = (w << 4) + cl;

  f32x4 acc[4];
  #pragma unroll
  for (int nf = 0; nf < 4; nf++) acc[nf] = (f32x4){0.f,0.f,0.f,0.f};

  for (int kk = 0; kk < 16; kk++){
    int c0k = kk << 5;
    {
      int n = t >> 2, cs8 = (t & 3) << 3;
      u16x8 v = *(const u16x8*)(xt + ((size_t)b*N_ + n0 + n)*C_ + c0k + cs8);
      *(u16x8*)&Al[n*40 + cs8] = v;
    }
    {
      int o = t >> 2, cs8 = (t & 3) << 3;
      const float* s = Wm + (size_t)(o0 + o)*C_ + c0k + cs8;
      f32x4 v0 = *(const f32x4*)s;
      f32x4 v1 = *(const f32x4*)(s + 4);
      u16x8 h;
      #pragma unroll
      for (int j = 0; j < 4; j++) h[j] = f2bf(v0[j]);
      #pragma unroll
      for (int j = 0; j < 4; j++) h[4+j] = f2bf(v1[j]);
      *(u16x8*)&Bl[o*40 + cs8] = h;
    }
    __syncthreads();
    bf16x8 bfr = *(const bf16x8*)&Bl[col*40 + (g << 3)];
    #pragma unroll
    for (int nf = 0; nf < 4; nf++){
      bf16x8 afr = *(const bf16x8*)&Al[((nf << 4) + cl)*40 + (g << 3)];
      acc[nf] = __builtin_amdgcn_mfma_f32_16x16x32_bf16(afr, bfr, acc[nf], 0, 0, 0);
    }
    __syncthreads();
  }

  float bvv = bias[o0 + col];
  #pragma unroll
  for (int nf = 0; nf < 4; nf++)
    #pragma unroll
    for (int rr = 0; rr < 4; rr++)
      T[((nf << 4) + (g << 2) + rr)*68 + col] = acc[nf][rr] + bvv;
  __syncthreads();

  if (MODE == 2){
    int o = t >> 2, j = t & 3;
    u16x8 h0, h1;
    #pragma unroll
    for (int ii = 0; ii < 8; ii++) h0[ii] = f2bf(T[(j*16+ii)*68 + o]);
    #pragma unroll
    for (int ii = 0; ii < 8; ii++) h1[ii] = f2bf(T[(j*16+8+ii)*68 + o]);
    unsigned short* d = outw + ((size_t)b*C_ + o0 + o)*N_ + n0 + (j << 4);
    *(u16x8*)d = h0;
    *(u16x8*)(d + 8) = h1;
  } else {
    int n = t >> 2, j = t & 3;
    float vals[16]; float s = 0.f;
    #pragma unroll
    for (int ii = 0; ii < 16; ii++){ vals[ii] = T[n*68 + (j << 4) + ii]; s += vals[ii]; }
    s += __shfl_xor(s, 1); s += __shfl_xor(s, 2);
    float mean = (MODE == 0) ? s * (1.f/64.f) : 0.f;
    float scl  = (MODE == 0) ? (1.f/512.f)    : 1.f;
    u16x8 h0, h1;
    #pragma unroll
    for (int ii = 0; ii < 8; ii++) h0[ii] = f2bf((vals[ii]   - mean) * scl);
    #pragma unroll
    for (int ii = 0; ii < 8; ii++) h1[ii] = f2bf((vals[8+ii] - mean) * scl);
    unsigned short* d = outw + ((size_t)b*N_ + n0 + n)*CQ + (j << 4);
    *(u16x8*)d = h0;
    *(u16x8*)(d + 8) = h1;
  }
}

// ---------------- flash attention + residual (1-barrier/step pipeline) ----------------
// grid: blockIdx = (qt*2 + chalf)*8 + b   -> 72*2*8 = 1152 blocks, 512 threads.
// Each block: Q-tile of 32 rows, c-half of 256 channels. KB=64, 36 steps.
// Wave-private K copy (16 m-rows) and V slice (32 c-rows); counted vmcnt waits.
__global__ __launch_bounds__(512) void k_attn(const unsigned short* __restrict__ qw,
                                              const unsigned short* __restrict__ kw,
                                              const unsigned short* __restrict__ vw,
                                              const float* __restrict__ x,
                                              const float* __restrict__ gamma_p,
                                              float* __restrict__ out){
  __shared__ __attribute__((aligned(16))) short Qs[32*64];     // [n][64 cq], chunk-rotated
  __shared__ __attribute__((aligned(16))) short Ks[2*64*64];   // 2 copies [m][64 cq]
  __shared__ __attribute__((aligned(16))) short Vs[256*64];    // [c_local][64 m]
  __shared__ __attribute__((aligned(16))) short Ps[2*32*64];   // dbuf [n][64 m]
  __shared__ __attribute__((aligned(16))) float lsums[32];

  int i = blockIdx.x;
  int b  = i & 7;
  int ch = (i >> 3) & 1;
  int qt = i >> 4;
  int n0 = qt << 5;

  int t = threadIdx.x; int w = t >> 6; int l = t & 63;
  int cl = l & 15, g = l >> 4;
  int lrow = l >> 3, lch = l & 7;
  int gc8 = ((lch - lrow) & 7) << 3;     // pre-swizzled source chunk (shorts)

  // ---- staging pointers (lane-resolved) ----
  const unsigned short* kp = kw + ((size_t)b*N_ + ((w & 3) << 4) + lrow)*CQ + gc8;   // + m0*64, + j*512
  const unsigned short* vp = vw + ((size_t)b*C_ + (ch << 8) + (w << 5) + lrow)*N_ + gc8; // + m0, + j*8*N_
  short* ldsK = Ks + ((w >> 2) << 12) + ((w & 3) << 10);   // + j*512
  short* ldsV = Vs + (w << 11);                            // + j*512

  // ---- prologue: stage Q, K(0), V(0) ----
  if (w < 4){
    const unsigned short* qp = qw + ((size_t)b*N_ + n0 + (w << 3) + lrow)*CQ + gc8;
    gload_lds16(qp, Qs + (w << 9));
  }
  gload_lds16(kp, ldsK);
  gload_lds16(kp + 512, ldsK + 512);
  #pragma unroll
  for (int j = 0; j < 4; j++) gload_lds16(vp + j*8*N_, ldsV + j*512);
  if (t < 32) lsums[t] = 0.f;
  __syncthreads();   // drains everything once; Q visible to all

  // ---- hoist Q fragments ----
  int nf = w >> 2, mf = w & 3;
  int qrow = (nf << 4) + cl;
  bf16x8 qf[2];
  #pragma unroll
  for (int ks = 0; ks < 2; ks++)
    qf[ks] = *(const bf16x8*)((const char*)Qs + qrow*128 + ((((ks << 2) + g) + qrow) & 7)*16);

  // ---- precomputed LDS read/write byte offsets ----
  const char* KsB = (const char*)(Ks + ((w >> 2) << 12));
  int krow = ((w & 3) << 4) + cl;
  int krd[2];
  #pragma unroll
  for (int ks = 0; ks < 2; ks++) krd[ks] = krow*128 + ((((ks << 2) + g) + krow) & 7)*16;
  int pm = (mf << 4) + cl;
  int pwo[4];
  #pragma unroll
  for (int rr = 0; rr < 4; rr++){
    int row = (nf << 4) + (g << 2) + rr;
    pwo[rr] = row*128 + (((pm >> 3) + row) & 7)*16 + (pm & 7)*2;
  }
  int pro[2][2], vro[2][2];
  #pragma unroll
  for (int nfp = 0; nfp < 2; nfp++)
    #pragma unroll
    for (int ks = 0; ks < 2; ks++){
      int prow = (nfp << 4) + cl;
      pro[nfp][ks] = prow*128 + ((((ks << 2) + g) + prow) & 7)*16;
    }
  #pragma unroll
  for (int cf = 0; cf < 2; cf++)
    #pragma unroll
    for (int ks = 0; ks < 2; ks++){
      int vrow = (w << 5) + (cf << 4) + cl;
      vro[cf][ks] = vrow*128 + ((((ks << 2) + g) + vrow) & 7)*16;
    }

  f32x4 acc[2][2];
  #pragma unroll
  for (int a = 0; a < 2; a++)
    #pragma unroll
    for (int c2 = 0; c2 < 2; c2++) acc[a][c2] = (f32x4){0.f,0.f,0.f,0.f};
  f32x4 lsum = (f32x4){0.f,0.f,0.f,0.f};

  for (int mt = 0; mt < 36; ++mt){
    char* PsB = (char*)Ps + ((mt & 1) << 12);
    int m1 = (mt == 35) ? 0 : (mt + 1) << 6;   // next-step m0 (wraps; wrap loads unread)

    // wait K(mt) landed (leave V(mt)'s 4 loads in flight)
    asm volatile("s_waitcnt vmcnt(4)" ::: "memory");
    __builtin_amdgcn_sched_barrier(0);

    // ---- S = Qc @ K^T : one 16x16 frag per wave ----
    f32x4 sv = (f32x4){0.f,0.f,0.f,0.f};
    {
      bf16x8 kf0 = *(const bf16x8*)(KsB + krd[0]);
      bf16x8 kf1 = *(const bf16x8*)(KsB + krd[1]);
      sv = __builtin_amdgcn_mfma_f32_16x16x32_bf16(qf[0], kf0, sv, 0, 0, 0);
      sv = __builtin_amdgcn_mfma_f32_16x16x32_bf16(qf[1], kf1, sv, 0, 0, 0);
    }
    // ---- exp (no max-shift: |s| << 1) + P write + row-sum partials ----
    #pragma unroll
    for (int rr = 0; rr < 4; rr++){
      float p = __expf(sv[rr]);
      lsum[rr] += p;
      *(unsigned short*)(PsB + pwo[rr]) = f2bf(p);
    }

    // own K reads + P writes complete, then issue K(mt+1) into own copy
    asm volatile("s_waitcnt lgkmcnt(0)" ::: "memory");
    __builtin_amdgcn_sched_barrier(0);
    gload_lds16(kp + (size_t)m1*CQ, ldsK);
    gload_lds16(kp + (size_t)m1*CQ + 512, ldsK + 512);

    __builtin_amdgcn_s_barrier();           // P[pt] published
    __builtin_amdgcn_sched_barrier(0);

    // wait V(mt) landed (leave K(mt+1)'s 2 loads in flight)
    asm volatile("s_waitcnt vmcnt(2)" ::: "memory");
    __builtin_amdgcn_sched_barrier(0);

    // ---- O += P @ V : 8 mfma on own 32-channel slice ----
    #pragma unroll
    for (int nfp = 0; nfp < 2; nfp++){
      bf16x8 pa0 = *(const bf16x8*)(PsB + pro[nfp][0]);
      bf16x8 pa1 = *(const bf16x8*)(PsB + pro[nfp][1]);
      #pragma unroll
      for (int cf = 0; cf < 2; cf++){
        bf16x8 vb0 = *(const bf16x8*)((const char*)Vs + vro[cf][0]);
        bf16x8 vb1 = *(const bf16x8*)((const char*)Vs + vro[cf][1]);
        acc[nfp][cf] = __builtin_amdgcn_mfma_f32_16x16x32_bf16(pa0, vb0, acc[nfp][cf], 0, 0, 0);
        acc[nfp][cf] = __builtin_amdgcn_mfma_f32_16x16x32_bf16(pa1, vb1, acc[nfp][cf], 0, 0, 0);
      }
    }

    // own V reads complete, then issue V(mt+1) into own slice
    asm volatile("s_waitcnt lgkmcnt(0)" ::: "memory");
    __builtin_amdgcn_sched_barrier(0);
    #pragma unroll
    for (int j = 0; j < 4; j++) gload_lds16(vp + m1 + j*8*N_, ldsV + j*512);
  }

  // ---- row-sum reduction: over 16 cols (cl) then over 4 mf-waves ----
  #pragma unroll
  for (int rr = 0; rr < 4; rr++){
    float v = lsum[rr];
    v += __shfl_xor(v, 1); v += __shfl_xor(v, 2);
    v += __shfl_xor(v, 4); v += __shfl_xor(v, 8);
    if (cl == 0) atomicAdd(&lsums[(nf << 4) + (g << 2) + rr], v);
  }
  __syncthreads();
  if (t < 32) lsums[t] = 1.f / lsums[t];
  __syncthreads();

  // ---- epilogue: out = gamma * (O / l) + x ----
  float gmv = gamma_p[0];
  #pragma unroll
  for (int nfp = 0; nfp < 2; nfp++){
    f32x4 li = *(const f32x4*)&lsums[(nfp << 4) + (g << 2)];
    #pragma unroll
    for (int cf = 0; cf < 2; cf++){
      int c = (ch << 8) + (w << 5) + (cf << 4) + cl;
      size_t base = ((size_t)b*C_ + c)*N_ + n0 + (nfp << 4) + (g << 2);
      f32x4 xv = *(const f32x4*)&x[base];
      f32x4 o4;
      #pragma unroll
      for (int rr = 0; rr < 4; rr++) o4[rr] = acc[nfp][cf][rr]*li[rr]*gmv + xv[rr];
      *(f32x4*)&out[base] = o4;
    }
  }
}

extern "C" void kernel_launch(void* const* d_in, const int* in_sizes, int n_in,
                              void* d_out, int out_size, void* d_ws, size_t ws_size,
                              hipStream_t stream) {
  (void)in_sizes; (void)n_in; (void)out_size; (void)ws_size;
  const float* x  = (const float*)d_in[0];
  const float* Wq = (const float*)d_in[1];
  const float* bq = (const float*)d_in[2];
  const float* Wk = (const float*)d_in[3];
  const float* bk = (const float*)d_in[4];
  const float* Wv = (const float*)d_in[5];
  const float* bv = (const float*)d_in[6];
  const float* gm = (const float*)d_in[7];
  float* out = (float*)d_out;

  unsigned short* xt = (unsigned short*)d_ws;                 // [B][N][C] bf16
  unsigned short* qw = xt + (size_t)B_*N_*C_;                 // [B][N][64] bf16
  unsigned short* kw = qw + (size_t)B_*N_*CQ;                 // [B][N][64] bf16
  unsigned short* vw = kw + (size_t)B_*N_*CQ;                 // [B][C][N] bf16

  k_transpose<<<2304, 256, 0, stream>>>(x, xt);
  k_proj<0><<<288, 256, 0, stream>>>(xt, Wq, bq, qw);
  k_proj<1><<<288, 256, 0, stream>>>(xt, Wk, bk, kw);
  k_proj<2><<<2304, 256, 0, stream>>>(xt, Wv, bv, vw);
  k_attn<<<1152, 512, 0, stream>>>(qw, kw, vw, x, gm, out);
}

// Round 3
// 177.679 us; speedup vs baseline: 1.7743x; 1.1072x over previous
//
#include <hip/hip_runtime.h>

#define B_ 8
#define C_ 512
#define N_ 2304
#define CQ 64

typedef float f32x4 __attribute__((ext_vector_type(4)));
typedef float f32x16 __attribute__((ext_vector_type(16)));
typedef short bf16x8 __attribute__((ext_vector_type(8)));
typedef unsigned short u16x8 __attribute__((ext_vector_type(8)));

__device__ __forceinline__ unsigned short f2bf(float f){
  union { float f; unsigned int u; } v; v.f = f;
  unsigned int r = (v.u + 0x7fffu + ((v.u >> 16) & 1u)) >> 16;
  return (unsigned short)r;
}

__device__ __forceinline__ void gload_lds16(const void* g, void* l){
  __builtin_amdgcn_global_load_lds(
      (const __attribute__((address_space(1))) unsigned int*)g,
      (__attribute__((address_space(3))) unsigned int*)l, 16, 0, 0);
}

// ---------------- transpose: x [B][C][N] f32 -> xt [B][N][C] bf16 ----------------
__global__ __launch_bounds__(256) void k_transpose(const float* __restrict__ x,
                                                   unsigned short* __restrict__ xt){
  __shared__ float T[64*68];
  int i = blockIdx.x;
  int b = i & 7; int r = i >> 3;          // r in [0, 288)
  int ct = r & 7, nt = r >> 3;            // 8 c-tiles, 36 n-tiles
  int c0 = ct << 6, n0 = nt << 6;
  int t = threadIdx.x;
  {
    int c = t >> 2, nn = (t & 3) << 4;
    const float* src = x + ((size_t)b*C_ + c0 + c)*N_ + n0 + nn;
    #pragma unroll
    for (int q = 0; q < 4; q++){
      f32x4 v = *(const f32x4*)(src + q*4);
      *(f32x4*)&T[c*68 + nn + q*4] = v;
    }
  }
  __syncthreads();
  {
    int n = t >> 2, cs = (t & 3) << 4;
    u16x8 h0, h1;
    #pragma unroll
    for (int ii = 0; ii < 8; ii++) h0[ii] = f2bf(T[(cs+ii)*68 + n]);
    #pragma unroll
    for (int ii = 0; ii < 8; ii++) h1[ii] = f2bf(T[(cs+8+ii)*68 + n]);
    unsigned short* d = xt + ((size_t)b*N_ + n0 + n)*C_ + c0 + cs;
    *(u16x8*)d = h0;
    *(u16x8*)(d + 8) = h1;
  }
}

// ---------------- projection GEMM: D_t[n,o] = sum_c xt[n,c] W[o,c] + b[o] ----------------
// MODE 0: Q -> center over o, scale log2e/512, store [B][N][64] bf16
// MODE 1: K -> store [B][N][64] bf16
// MODE 2: V -> store [B][C][N] bf16 with m-permutation (bit2<->bit3 within 32-blocks of n)
template<int MODE>
__global__ __launch_bounds__(256) void k_proj(const unsigned short* __restrict__ xt,
                                              const float* __restrict__ Wm,
                                              const float* __restrict__ bias,
                                              unsigned short* __restrict__ outw){
  __shared__ short Al[64*40];
  __shared__ short Bl[64*40];
  __shared__ float T[64*68];
  int i = blockIdx.x;
  int b = i & 7; int r = i >> 3;
  int nt, o0;
  if (MODE == 2){ nt = r >> 3; o0 = (r & 7) << 6; } else { nt = r; o0 = 0; }
  int n0 = nt << 6;
  int t = threadIdx.x; int w = t >> 6; int l = t & 63;
  int cl = l & 15, g = l >> 4;
  int col = (w << 4) + cl;

  f32x4 acc[4];
  #pragma unroll
  for (int nf = 0; nf < 4; nf++) acc[nf] = (f32x4){0.f,0.f,0.f,0.f};

  for (int kk = 0; kk < 16; kk++){
    int c0k = kk << 5;
    {
      int n = t >> 2, cs8 = (t & 3) << 3;
      u16x8 v = *(const u16x8*)(xt + ((size_t)b*N_ + n0 + n)*C_ + c0k + cs8);
      *(u16x8*)&Al[n*40 + cs8] = v;
    }
    {
      int o = t >> 2, cs8 = (t & 3) << 3;
      const float* s = Wm + (size_t)(o0 + o)*C_ + c0k + cs8;
      f32x4 v0 = *(const f32x4*)s;
      f32x4 v1 = *(const f32x4*)(s + 4);
      u16x8 h;
      #pragma unroll
      for (int j = 0; j < 4; j++) h[j] = f2bf(v0[j]);
      #pragma unroll
      for (int j = 0; j < 4; j++) h[4+j] = f2bf(v1[j]);
      *(u16x8*)&Bl[o*40 + cs8] = h;
    }
    __syncthreads();
    bf16x8 bfr = *(const bf16x8*)&Bl[col*40 + (g << 3)];
    #pragma unroll
    for (int nf = 0; nf < 4; nf++){
      bf16x8 afr = *(const bf16x8*)&Al[((nf << 4) + cl)*40 + (g << 3)];
      acc[nf] = __builtin_amdgcn_mfma_f32_16x16x32_bf16(afr, bfr, acc[nf], 0, 0, 0);
    }
    __syncthreads();
  }

  float bvv = bias[o0 + col];
  #pragma unroll
  for (int nf = 0; nf < 4; nf++)
    #pragma unroll
    for (int rr = 0; rr < 4; rr++)
      T[((nf << 4) + (g << 2) + rr)*68 + col] = acc[nf][rr] + bvv;
  __syncthreads();

  if (MODE == 2){
    int o = t >> 2, j = t & 3;
    u16x8 h0, h1;
    // permuted read: stored position p holds true n-offset swap23(p) within 32-block
    #pragma unroll
    for (int ii = 0; ii < 8; ii++){
      int q2 = (ii & 3) | ((ii & 4) << 1);          // 0,1,2,3,8,9,10,11
      h0[ii] = f2bf(T[(j*16 + q2)*68 + o]);
    }
    #pragma unroll
    for (int ii = 0; ii < 8; ii++){
      int q2 = ((ii & 3) | ((ii & 4) << 1)) + 4;    // 4,5,6,7,12,13,14,15
      h1[ii] = f2bf(T[(j*16 + q2)*68 + o]);
    }
    unsigned short* d = outw + ((size_t)b*C_ + o0 + o)*N_ + n0 + (j << 4);
    *(u16x8*)d = h0;
    *(u16x8*)(d + 8) = h1;
  } else {
    int n = t >> 2, j = t & 3;
    float vals[16]; float s = 0.f;
    #pragma unroll
    for (int ii = 0; ii < 16; ii++){ vals[ii] = T[n*68 + (j << 4) + ii]; s += vals[ii]; }
    s += __shfl_xor(s, 1); s += __shfl_xor(s, 2);
    float mean = (MODE == 0) ? s * (1.f/64.f) : 0.f;
    float scl  = (MODE == 0) ? (1.44269504089f/512.f) : 1.f;   // fold log2e for exp2
    u16x8 h0, h1;
    #pragma unroll
    for (int ii = 0; ii < 8; ii++) h0[ii] = f2bf((vals[ii]   - mean) * scl);
    #pragma unroll
    for (int ii = 0; ii < 8; ii++) h1[ii] = f2bf((vals[8+ii] - mean) * scl);
    unsigned short* d = outw + ((size_t)b*N_ + n0 + n)*CQ + (j << 4);
    *(u16x8*)d = h0;
    *(u16x8*)(d + 8) = h1;
  }
}

// ---------------- flash attention + residual, register-P, 32x32 MFMA ----------------
// grid: i = ((qp*4 + cs)*8 + b), 36*4*8 = 1152 blocks, 128 threads (2 waves).
// wave w: q-rows n0+w*32 (own S^T/P in registers); both waves share c-slice cs*128
// and the K/V LDS tiles (double-buffered). KB=32, 72 steps, 1 barrier/step.
__global__ __launch_bounds__(128, 2) void k_attn(const unsigned short* __restrict__ qw,
                                                 const unsigned short* __restrict__ kw,
                                                 const unsigned short* __restrict__ vw,
                                                 const float* __restrict__ x,
                                                 const float* __restrict__ gamma_p,
                                                 float* __restrict__ out){
  __shared__ __attribute__((aligned(16))) short Ks[2][32*64];    // [m 0..31][cq 64], rotate-swizzled
  __shared__ __attribute__((aligned(16))) short Vs[2][32*128];   // rows r: c in {r,r+32,r+64,r+96} x 32 m

  int i = blockIdx.x;
  int b  = i & 7;
  int cs = (i >> 3) & 3;
  int qp = i >> 5;                 // 0..35
  int c0 = cs << 7;
  int t = threadIdx.x; int w = t >> 6; int l = t & 63;
  int h = l >> 5;                  // lane half
  int n = l & 31;                  // q-row within wave tile / output col
  int n0w = (qp << 6) + (w << 5);

  const size_t bN = (size_t)b * N_;
  const unsigned short* kwb = kw + bN * CQ;
  const unsigned short* vwb = vw + (size_t)b * C_ * N_;

  // ---- Q fragments (B-operand): lane holds Q[n][cq = kq*16 + h*8 + j] ----
  bf16x8 qf[4];
  #pragma unroll
  for (int kq = 0; kq < 4; kq++)
    qf[kq] = *(const bf16x8*)(qw + (bN + n0w + n)*CQ + kq*16 + h*8);

  // ---- staging lane constants (pre-swizzled global source, linear LDS dest) ----
  int kro[2];
  #pragma unroll
  for (int jj = 0; jj < 2; jj++){
    int g = 2*w + jj;
    int r = 8*g + (l >> 3);
    int lc = ((l & 7) - r) & 7;
    kro[jj] = r*CQ + lc*8;                         // + m0*CQ
  }
  int vro[4];
  #pragma unroll
  for (int jj = 0; jj < 4; jj++){
    int g = 4*w + jj;
    int r = 4*g + (l >> 4);
    int lc = ((l & 15) - r) & 15;
    vro[jj] = (c0 + (lc >> 2)*32 + r)*N_ + (lc & 3)*8;   // + m0
  }
  // ---- LDS read byte offsets ----
  int ko[4];
  #pragma unroll
  for (int kq = 0; kq < 4; kq++){
    int lc = kq*2 + h;
    ko[kq] = n*128 + (((lc + n) & 7) << 4);
  }
  int vo[4][2];
  #pragma unroll
  for (int ct = 0; ct < 4; ct++)
    #pragma unroll
    for (int s = 0; s < 2; s++){
      int lc = ct*4 + s*2 + h;
      vo[ct][s] = n*256 + (((lc + n) & 15) << 4);
    }

  f32x16 acc[4];
  #pragma unroll
  for (int ct = 0; ct < 4; ct++)
    #pragma unroll
    for (int rr = 0; rr < 16; rr++) acc[ct][rr] = 0.f;
  float lsum = 0.f;

  // ---- prologue: stage tile 0 ----
  #pragma unroll
  for (int jj = 0; jj < 2; jj++)
    gload_lds16(kwb + kro[jj], &Ks[0][(2*w + jj) << 9]);
  #pragma unroll
  for (int jj = 0; jj < 4; jj++)
    gload_lds16(vwb + vro[jj], &Vs[0][(4*w + jj) << 9]);
  __syncthreads();

  for (int mt = 0; mt < 72; mt++){
    int p = mt & 1;
    int m1 = (mt == 71) ? 0 : ((mt + 1) << 5);
    // issue staging for t+1 into parity^1 (drained by end-of-step barrier)
    #pragma unroll
    for (int jj = 0; jj < 2; jj++)
      gload_lds16(kwb + (size_t)m1*CQ + kro[jj], &Ks[p^1][(2*w + jj) << 9]);
    #pragma unroll
    for (int jj = 0; jj < 4; jj++)
      gload_lds16(vwb + m1 + vro[jj], &Vs[p^1][(4*w + jj) << 9]);
    __builtin_amdgcn_sched_barrier(0);

    // ---- S^T = mfma(K, Qc): lane holds S^T[m-rows][n = lane&31] ----
    f32x16 sv;
    #pragma unroll
    for (int rr = 0; rr < 16; rr++) sv[rr] = 0.f;
    const char* KsB = (const char*)Ks[p];
    #pragma unroll
    for (int kq = 0; kq < 4; kq++){
      bf16x8 kf = *(const bf16x8*)(KsB + ko[kq]);
      sv = __builtin_amdgcn_mfma_f32_32x32x16_bf16(kf, qf[kq], sv, 0, 0, 0);
    }
    // ---- P = 2^S (log2e pre-folded), row-sum partials, pack to bf16 ----
    float e[16];
    #pragma unroll
    for (int rr = 0; rr < 16; rr++) e[rr] = exp2f(sv[rr]);
    #pragma unroll
    for (int rr = 0; rr < 16; rr++) lsum += e[rr];
    unsigned int pd[8];
    #pragma unroll
    for (int j = 0; j < 8; j++)
      asm("v_cvt_pk_bf16_f32 %0, %1, %2" : "=v"(pd[j]) : "v"(e[2*j]), "v"(e[2*j+1]));
    union { unsigned int u[4]; bf16x8 v; } p0u, p1u;
    #pragma unroll
    for (int j = 0; j < 4; j++){ p0u.u[j] = pd[j]; p1u.u[j] = pd[4+j]; }

    // ---- O += V @ P : D[c][n], A = V frags from LDS, B = P in registers ----
    const char* VsB = (const char*)Vs[p];
    #pragma unroll
    for (int ct = 0; ct < 4; ct++){
      bf16x8 v0 = *(const bf16x8*)(VsB + vo[ct][0]);
      acc[ct] = __builtin_amdgcn_mfma_f32_32x32x16_bf16(v0, p0u.v, acc[ct], 0, 0, 0);
      bf16x8 v1 = *(const bf16x8*)(VsB + vo[ct][1]);
      acc[ct] = __builtin_amdgcn_mfma_f32_32x32x16_bf16(v1, p1u.v, acc[ct], 0, 0, 0);
    }
    __syncthreads();   // publishes t+1 tiles (drains staging vmcnt) 
  }

  // ---- epilogue: out = gamma * (O / l) + x ----
  float ls = lsum + __shfl_xor(lsum, 32);
  float f = gamma_p[0] / ls;
  #pragma unroll
  for (int ct = 0; ct < 4; ct++){
    #pragma unroll
    for (int rr = 0; rr < 16; rr++){
      int c = c0 + ct*32 + (rr & 3) + ((rr >> 2) << 3) + (h << 2);
      size_t idx = ((size_t)b*C_ + c)*N_ + n0w + n;
      out[idx] = acc[ct][rr] * f + x[idx];
    }
  }
}

extern "C" void kernel_launch(void* const* d_in, const int* in_sizes, int n_in,
                              void* d_out, int out_size, void* d_ws, size_t ws_size,
                              hipStream_t stream) {
  (void)in_sizes; (void)n_in; (void)out_size; (void)ws_size;
  const float* x  = (const float*)d_in[0];
  const float* Wq = (const float*)d_in[1];
  const float* bq = (const float*)d_in[2];
  const float* Wk = (const float*)d_in[3];
  const float* bk = (const float*)d_in[4];
  const float* Wv = (const float*)d_in[5];
  const float* bv = (const float*)d_in[6];
  const float* gm = (const float*)d_in[7];
  float* out = (float*)d_out;

  unsigned short* xt = (unsigned short*)d_ws;                 // [B][N][C] bf16
  unsigned short* qw = xt + (size_t)B_*N_*C_;                 // [B][N][64] bf16 (centered, *log2e/512)
  unsigned short* kw = qw + (size_t)B_*N_*CQ;                 // [B][N][64] bf16
  unsigned short* vw = kw + (size_t)B_*N_*CQ;                 // [B][C][N] bf16 (m-permuted)

  k_transpose<<<2304, 256, 0, stream>>>(x, xt);
  k_proj<0><<<288, 256, 0, stream>>>(xt, Wq, bq, qw);
  k_proj<1><<<288, 256, 0, stream>>>(xt, Wk, bk, kw);
  k_proj<2><<<2304, 256, 0, stream>>>(xt, Wv, bv, vw);
  k_attn<<<1152, 128, 0, stream>>>(qw, kw, vw, x, gm, out);
}